// Round 6
// baseline (2159.212 us; speedup 1.0000x reference)
//
#include <hip/hip_runtime.h>
#include <hip/hip_bf16.h>
#include <cstdint>
#include <cstddef>

#define N_ROWS 8192
#define N_COLS 8192
#define NUM_ITER 48             // bit-exact at 120 bounds rate: err@48 <= ~2e-4 << 2e-3
#define ROWS_A 32               // rows per block in kern_A
#define THR_A 1024              // threads per block in kern_A (1 uint4 of K per thread)
#define BLK_A (N_ROWS / ROWS_A) // 256 blocks x 1024 thr -> 1 block/CU = 16 waves/CU
#define ROWS_L 16
#define BLK_L (N_ROWS / ROWS_L)
// vpart is stored f16. Raw partials are ~1e-7 (f16-subnormal territory), so
// accumulate u*VSCALE and divide the scale back out in kern_B. Worst-case
// partial ~32 * 6.5e-4 * VSCALE = 2.2e4 < 65504 (f16 max): no overflow.
#define VSCALE 1048576.0f       // 2^20

typedef _Float16 half2_t __attribute__((ext_vector_type(2)));

__device__ __forceinline__ half2_t u2h(unsigned x) {
    union { unsigned u; half2_t h; } c; c.u = x; return c.h;
}

__device__ __forceinline__ float fdot2(half2_t a, half2_t b, float c) {
#if __has_builtin(__builtin_amdgcn_fdot2)
    return __builtin_amdgcn_fdot2(a, b, c, false);
#else
    return c + (float)a.x * (float)b.x + (float)a.y * (float)b.y;
#endif
}

// ---------- setup: inv sums of a,b; zero loss acc; v = 1 (f16) ----------
__global__ __launch_bounds__(256) void kern_setup(const float* __restrict__ a,
                                                  const float* __restrict__ b,
                                                  float* __restrict__ scal,
                                                  _Float16* __restrict__ v) {
    const int t = threadIdx.x, blk = blockIdx.x;
    if (blk < 2) {
        const float* x = blk ? b : a;
        float s = 0.f;
        #pragma unroll
        for (int k = 0; k < 32; ++k) s += x[t + 256 * k];
        #pragma unroll
        for (int o = 32; o > 0; o >>= 1) s += __shfl_down(s, o);
        __shared__ float red[4];
        if ((t & 63) == 0) red[t >> 6] = s;
        __syncthreads();
        if (t == 0) {
            float tot = red[0] + red[1] + red[2] + red[3];
            scal[blk] = 1.0f / tot;
            if (blk == 0) scal[2] = 0.f;   // loss accumulator
        }
    } else {
        v[(blk - 2) * 256 + t] = (_Float16)1.0f;
    }
}

// ---------- K = exp(-M/eps) as f16, 8 elems/thread ----------
__global__ __launch_bounds__(256) void kern_kbuild(const float* __restrict__ M,
                                                   unsigned short* __restrict__ K) {
    size_t idx = ((size_t)blockIdx.x * 256 + threadIdx.x) * 8;
    const float4* mp = (const float4*)(M + idx);
    float4 m0 = mp[0], m1 = mp[1];
    float f[8] = { m0.x, m0.y, m0.z, m0.w, m1.x, m1.y, m1.z, m1.w };
    union { _Float16 h[8]; uint4 v; } pk;
    #pragma unroll
    for (int e = 0; e < 8; ++e) pk.h[e] = (_Float16)__expf(f[e] * -10.0f);
    *(uint4*)(K + idx) = pk.v;
}

// ---------- fused iteration: u = a/(K v); vpart[blk][j] = VSCALE * sum_i u_i K_ij ----------
// 256 blocks x 32 rows x 1024 threads; thread t owns cols 8t..8t+7 (one uint4
// of f16 K per row). f16 K + fdot2 for the dot; next row's K prefetched before
// the reduction so the barrier covers its latency. (Persistent-kernel grid
// barrier tried r3/r4: L2-invalidate storms on 8 non-coherent XCDs, 2.7x
// slower — reverted. Strided 16B kern_B tried r5: 64 lines/wave request,
// +374 us — reverted.)
__global__ __launch_bounds__(THR_A, 4) void kern_A(const unsigned short* __restrict__ K,
                                                   const float* __restrict__ a,
                                                   const float* __restrict__ scal,
                                                   const _Float16* __restrict__ v_in,
                                                   float* __restrict__ u_out,
                                                   _Float16* __restrict__ vpart) {
    const int t = threadIdx.x;
    const int row0 = blockIdx.x * ROWS_A;
    const float inv_sa = scal[0];

    half2_t vh[4];
    {
        uint4 rv = *(const uint4*)(v_in + 8 * t);
        vh[0] = u2h(rv.x); vh[1] = u2h(rv.y);
        vh[2] = u2h(rv.z); vh[3] = u2h(rv.w);
    }
    float acc[8];
    #pragma unroll
    for (int j = 0; j < 8; ++j) acc[j] = 0.f;

    uint4 raw, nxt;
    raw = ((const uint4*)(K + (size_t)row0 * N_COLS))[t];

    __shared__ float red[2][16];
    #pragma unroll 1
    for (int r = 0; r < ROWS_A; ++r) {
        const int i = row0 + r;
        if (r + 1 < ROWS_A) {                 // prefetch next row (latency hidden by
            nxt = ((const uint4*)(K + (size_t)(i + 1) * N_COLS))[t];
        }                                     //  dot + butterfly + barrier below)
        float dot = 0.f;
        dot = fdot2(u2h(raw.x), vh[0], dot);
        dot = fdot2(u2h(raw.y), vh[1], dot);
        dot = fdot2(u2h(raw.z), vh[2], dot);
        dot = fdot2(u2h(raw.w), vh[3], dot);
        #pragma unroll
        for (int m = 32; m > 0; m >>= 1) dot += __shfl_xor(dot, m);
        if ((t & 63) == 0) red[r & 1][t >> 6] = dot;
        __syncthreads();
        float s = 0.f;
        #pragma unroll
        for (int g = 0; g < 16; ++g) s += red[r & 1][g];
        const float u = a[i] * inv_sa / s;
        if (t == 0) u_out[i] = u;
        const float us = u * VSCALE;          // scale once per row, not per store
        {
            half2_t h0 = u2h(raw.x), h1 = u2h(raw.y);
            half2_t h2 = u2h(raw.z), h3 = u2h(raw.w);
            acc[0] += us * (float)h0.x; acc[1] += us * (float)h0.y;
            acc[2] += us * (float)h1.x; acc[3] += us * (float)h1.y;
            acc[4] += us * (float)h2.x; acc[5] += us * (float)h2.y;
            acc[6] += us * (float)h3.x; acc[7] += us * (float)h3.y;
        }
        raw = nxt;
    }

    {
        _Float16* vp = vpart + (size_t)blockIdx.x * N_COLS;
        union { _Float16 h[8]; uint4 v; } pk;
        #pragma unroll
        for (int e = 0; e < 8; ++e) pk.h[e] = (_Float16)acc[e];
        *(uint4*)(vp + 8 * t) = pk.v;
    }
}

// ---------- reduce partials: v_j = b_j * VSCALE / sum_p vpart[p][j]  (store f16) ----------
// Round-2-proven shape: lanes 0-31 read 32 CONSECUTIVE cols (one 64B line per
// half-wave); the 32 per-thread loads are independent (all in flight, MLP).
__global__ __launch_bounds__(256) void kern_B(const _Float16* __restrict__ vpart,
                                              const float* __restrict__ b,
                                              const float* __restrict__ scal,
                                              _Float16* __restrict__ v_out) {
    const int t = threadIdx.x;
    const int col0 = blockIdx.x * 32;
    const int c = t & 31, seg = t >> 5;        // 8 segments
    const int pstep = BLK_A / 8;               // 32
    const _Float16* base = vpart + (size_t)(seg * pstep) * N_COLS + col0 + c;
    float s = 0.f;
    #pragma unroll 16
    for (int p = 0; p < pstep; ++p) s += (float)base[(size_t)p * N_COLS];
    __shared__ float lds[8][32];
    lds[seg][c] = s;
    __syncthreads();
    if (t < 32) {
        float tot = 0.f;
        #pragma unroll
        for (int g = 0; g < 8; ++g) tot += lds[g][t];
        const int j = col0 + t;
        v_out[j] = (_Float16)(b[j] * scal[1] * VSCALE / tot);
    }
}

// ---------- loss = sum_ij u_i K_ij v_j M_ij, with M = -eps*ln(K) ----------
// Reads the 128 MB f16 K (LLC-warm from the last iteration) instead of the
// cold 256 MB fp32 M: loss = -0.1 * sum u v K lnK.
__global__ __launch_bounds__(256) void kern_loss(const unsigned short* __restrict__ K,
                                                 const float* __restrict__ u_in,
                                                 const _Float16* __restrict__ v_in,
                                                 float* __restrict__ scal) {
    const int t = threadIdx.x;
    const int row0 = blockIdx.x * ROWS_L;
    float vreg[32];
    #pragma unroll
    for (int k = 0; k < 4; ++k) {
        uint4 rv = *(const uint4*)(v_in + 8 * t + 2048 * k);
        half2_t h0 = u2h(rv.x), h1 = u2h(rv.y), h2 = u2h(rv.z), h3 = u2h(rv.w);
        vreg[8*k+0] = (float)h0.x; vreg[8*k+1] = (float)h0.y;
        vreg[8*k+2] = (float)h1.x; vreg[8*k+3] = (float)h1.y;
        vreg[8*k+4] = (float)h2.x; vreg[8*k+5] = (float)h2.y;
        vreg[8*k+6] = (float)h3.x; vreg[8*k+7] = (float)h3.y;
    }
    float acc = 0.f;
    for (int r = 0; r < ROWS_L; ++r) {
        const int i = row0 + r;
        const float ui = u_in[i];
        const uint4* Kp = (const uint4*)(K + (size_t)i * N_COLS);
        #pragma unroll
        for (int k = 0; k < 4; ++k) {
            uint4 rk = Kp[t + 256 * k];
            half2_t h0 = u2h(rk.x), h1 = u2h(rk.y), h2 = u2h(rk.z), h3 = u2h(rk.w);
            float kf[8] = { (float)h0.x, (float)h0.y, (float)h1.x, (float)h1.y,
                            (float)h2.x, (float)h2.y, (float)h3.x, (float)h3.y };
            #pragma unroll
            for (int e = 0; e < 8; ++e) {
                acc += (ui * vreg[8*k+e]) * kf[e] * __logf(kf[e]);
            }
        }
    }
    acc *= -0.1f;   // M = -eps * ln(K), eps = 0.1
    #pragma unroll
    for (int o = 32; o > 0; o >>= 1) acc += __shfl_down(acc, o);
    __shared__ float red[4];
    if ((t & 63) == 0) red[t >> 6] = acc;
    __syncthreads();
    if (t == 0) atomicAdd(&scal[2], red[0] + red[1] + red[2] + red[3]);
}

__global__ void kern_out(const float* __restrict__ scal, float* __restrict__ out) {
    if (threadIdx.x == 0 && blockIdx.x == 0) out[0] = scal[2];
}

// ---------- launch ----------
extern "C" void kernel_launch(void* const* d_in, const int* in_sizes, int n_in,
                              void* d_out, int out_size, void* d_ws, size_t ws_size,
                              hipStream_t stream) {
    const float* a = (const float*)d_in[0];
    const float* b = (const float*)d_in[1];
    const float* M = (const float*)d_in[2];

    char* ws = (char*)d_ws;
    float* scal       = (float*)ws;                                  // scalars
    float* u          = (float*)(ws + 1024);                         // 32 KB
    _Float16* v       = (_Float16*)(ws + 1024 + 32768);              // 16 KB
    _Float16* vpart   = (_Float16*)(ws + 1024 + 32768 + 16384);      // 256*8192*2 = 4 MB
    unsigned short* K = (unsigned short*)(ws + 1024 + 32768 + 16384 +
                                          (size_t)BLK_A * N_COLS * 2); // 128 MB f16

    kern_setup<<<dim3(34), dim3(256), 0, stream>>>(a, b, scal, v);
    kern_kbuild<<<dim3(32768), dim3(256), 0, stream>>>(M, K);
    for (int it = 0; it < NUM_ITER; ++it) {
        kern_A<<<dim3(BLK_A), dim3(THR_A), 0, stream>>>(K, a, scal, v, u, vpart);
        kern_B<<<dim3(256), dim3(256), 0, stream>>>(vpart, b, scal, v);
    }
    kern_loss<<<dim3(BLK_L), dim3(256), 0, stream>>>(K, u, v, scal);
    kern_out<<<dim3(1), dim3(64), 0, stream>>>(scal, (float*)d_out);
}

// Round 7
// 1808.091 us; speedup vs baseline: 1.1942x; 1.1942x over previous
//
#include <hip/hip_runtime.h>
#include <hip/hip_bf16.h>
#include <cstdint>
#include <cstddef>

#define N_ROWS 8192
#define N_COLS 8192
#define NUM_ITER 48             // bit-exact at 120 bounds rate: err@48 <= ~2e-4 << 2e-3
#define ROWS_A 16               // rows per block in kern_A  (round-2 proven geometry)
#define THR_A 512               // threads per block in kern_A
#define BLK_A (N_ROWS / ROWS_A) // 512 blocks x 512 thr -> 2+ blocks/CU (barrier overlap)
#define ROWS_L 16
#define BLK_L (N_ROWS / ROWS_L)
// K stored fp8 e4m3 scaled by 448: K*448 in [0.0203, 448] = all NORMAL e4m3
// (min normal 2^-6, max 448). Decode trick: f16(bits=(b&0x7f)<<7 | s<<15) is
// EXACTLY e4m3(b) * 2^-8, so decoded = K * 448/256 = K * 1.75 (fold 1.75 into
// the scalars). Half-ulp rel err 3.1% -> pi-weighted loss err ~5e-5 << 2e-3.
// vpart f16 with VSCALE shift: worst partial 1.75*16*6.5e-4*2^20 = 1.9e4 < 65504.
#define VSCALE 1048576.0f       // 2^20
#define KDEC 1.75f              // decoded f16 = KDEC * K

typedef _Float16 half2_t __attribute__((ext_vector_type(2)));

__device__ __forceinline__ half2_t u2h(unsigned x) {
    union { unsigned u; half2_t h; } c; c.u = x; return c.h;
}

// two e4m3 bytes (bits 7..0, 15..8 of d) -> f16 pair = e4m3 * 2^-8, exact
__device__ __forceinline__ half2_t fp8pair_to_h2(unsigned d) {
    unsigned w = ((d & 0x007fu) << 7)  | ((d & 0x0080u) << 8)
               | ((d & 0x7f00u) << 15) | ((d & 0x8000u) << 16);
    return u2h(w);
}

__device__ __forceinline__ float fdot2(half2_t a, half2_t b, float c) {
#if __has_builtin(__builtin_amdgcn_fdot2)
    return __builtin_amdgcn_fdot2(a, b, c, false);
#else
    return c + (float)a.x * (float)b.x + (float)a.y * (float)b.y;
#endif
}

// ---------- setup: inv sums of a,b; zero loss acc; v = 1 (f16) ----------
__global__ __launch_bounds__(256) void kern_setup(const float* __restrict__ a,
                                                  const float* __restrict__ b,
                                                  float* __restrict__ scal,
                                                  _Float16* __restrict__ v) {
    const int t = threadIdx.x, blk = blockIdx.x;
    if (blk < 2) {
        const float* x = blk ? b : a;
        float s = 0.f;
        #pragma unroll
        for (int k = 0; k < 32; ++k) s += x[t + 256 * k];
        #pragma unroll
        for (int o = 32; o > 0; o >>= 1) s += __shfl_down(s, o);
        __shared__ float red[4];
        if ((t & 63) == 0) red[t >> 6] = s;
        __syncthreads();
        if (t == 0) {
            float tot = red[0] + red[1] + red[2] + red[3];
            scal[blk] = 1.0f / tot;
            if (blk == 0) scal[2] = 0.f;   // loss accumulator
        }
    } else {
        v[(blk - 2) * 256 + t] = (_Float16)1.0f;
    }
}

// ---------- K8 = e4m3(448 * exp(-M/eps)), 8 elems/thread ----------
// f32 -> f16 (RN) -> RNE-truncate 10->3 mantissa bits. All outputs normal e4m3.
__global__ __launch_bounds__(256) void kern_kbuild(const float* __restrict__ M,
                                                   unsigned char* __restrict__ K8) {
    size_t idx = ((size_t)blockIdx.x * 256 + threadIdx.x) * 8;
    const float4* mp = (const float4*)(M + idx);
    float4 m0 = mp[0], m1 = mp[1];
    float f[8] = { m0.x, m0.y, m0.z, m0.w, m1.x, m1.y, m1.z, m1.w };
    unsigned b[8];
    #pragma unroll
    for (int e = 0; e < 8; ++e) {
        _Float16 h = (_Float16)(__expf(f[e] * -10.0f) * 448.0f);
        union { _Float16 h; unsigned short u; } c; c.h = h;
        unsigned mag = c.u & 0x7fffu;
        unsigned t2 = mag + 0x3fu + ((mag >> 7) & 1u);   // RNE at bit 7
        b[e] = ((t2 >> 7) - 64u) & 0xffu;                // K>0 so sign bit = 0
    }
    unsigned lo = b[0] | (b[1] << 8) | (b[2] << 16) | (b[3] << 24);
    unsigned hi = b[4] | (b[5] << 8) | (b[6] << 16) | (b[7] << 24);
    *(uint2*)(K8 + idx) = make_uint2(lo, hi);
}

// ---------- fused iteration: u = a/(K v); vpart[blk][j] = VSCALE * sum_i u_i K_ij ----------
// Round-2 geometry (512 blk x 512 thr x 16 rows; 2+ blocks/CU so the per-row
// barrier overlaps with the other block — r6 showed 1024-thr/1-block-per-CU
// exposes barrier latency, +9 us/iter). Thread t owns cols 16t..16t+15 = ONE
// uint4 of fp8 per row; decode to f16 pairs (exact, = 1.75*K) -> fdot2.
__global__ __launch_bounds__(THR_A, 4) void kern_A(const unsigned char* __restrict__ K8,
                                                   const float* __restrict__ a,
                                                   const float* __restrict__ scal,
                                                   const _Float16* __restrict__ v_in,
                                                   float* __restrict__ u_out,
                                                   _Float16* __restrict__ vpart) {
    const int t = threadIdx.x;
    const int row0 = blockIdx.x * ROWS_A;
    const float inv_sa = scal[0] * KDEC;      // fold decode scale into u

    half2_t vh[8];
    {
        uint4 rv0 = *(const uint4*)(v_in + 16 * t);
        uint4 rv1 = *(const uint4*)(v_in + 16 * t + 8);
        vh[0] = u2h(rv0.x); vh[1] = u2h(rv0.y); vh[2] = u2h(rv0.z); vh[3] = u2h(rv0.w);
        vh[4] = u2h(rv1.x); vh[5] = u2h(rv1.y); vh[6] = u2h(rv1.z); vh[7] = u2h(rv1.w);
    }
    float acc[16];
    #pragma unroll
    for (int j = 0; j < 16; ++j) acc[j] = 0.f;

    uint4 raw, nxt;
    raw = ((const uint4*)(K8 + (size_t)row0 * N_COLS))[t];

    __shared__ float red[2][8];
    #pragma unroll 1
    for (int r = 0; r < ROWS_A; ++r) {
        const int i = row0 + r;
        if (r + 1 < ROWS_A) {                 // prefetch next row (latency hidden by
            nxt = ((const uint4*)(K8 + (size_t)(i + 1) * N_COLS))[t];
        }                                     //  dot + butterfly + barrier below)
        half2_t kh[8];
        kh[0] = fp8pair_to_h2(raw.x); kh[1] = fp8pair_to_h2(raw.x >> 16);
        kh[2] = fp8pair_to_h2(raw.y); kh[3] = fp8pair_to_h2(raw.y >> 16);
        kh[4] = fp8pair_to_h2(raw.z); kh[5] = fp8pair_to_h2(raw.z >> 16);
        kh[6] = fp8pair_to_h2(raw.w); kh[7] = fp8pair_to_h2(raw.w >> 16);
        float dot = 0.f;
        #pragma unroll
        for (int p = 0; p < 8; ++p) dot = fdot2(kh[p], vh[p], dot);
        #pragma unroll
        for (int m = 32; m > 0; m >>= 1) dot += __shfl_xor(dot, m);
        if ((t & 63) == 0) red[r & 1][t >> 6] = dot;
        __syncthreads();
        float s = 0.f;
        #pragma unroll
        for (int g = 0; g < 8; ++g) s += red[r & 1][g];
        const float u = a[i] * inv_sa / s;    // s = KDEC*(Kv) -> u exact
        if (t == 0) u_out[i] = u;
        const float us = u * VSCALE;          // acc accumulates KDEC*VSCALE*u*K
        #pragma unroll
        for (int p = 0; p < 8; ++p) {
            acc[2*p]   += us * (float)kh[p].x;
            acc[2*p+1] += us * (float)kh[p].y;
        }
        raw = nxt;
    }

    {
        _Float16* vp = vpart + (size_t)blockIdx.x * N_COLS + 16 * t;
        union { _Float16 h[8]; uint4 v; } pk;
        #pragma unroll
        for (int e = 0; e < 8; ++e) pk.h[e] = (_Float16)acc[e];
        *(uint4*)vp = pk.v;
        #pragma unroll
        for (int e = 0; e < 8; ++e) pk.h[e] = (_Float16)acc[8 + e];
        *(uint4*)(vp + 8) = pk.v;
    }
}

// ---------- reduce partials: v_j = b_j*KDEC*VSCALE / sum_p vpart[p][j]  (store f16) ----------
// Round-2-proven shape: lanes read 32 CONSECUTIVE cols (1 line per half-wave),
// 64 independent strided loads all in flight (MLP).
__global__ __launch_bounds__(256) void kern_B(const _Float16* __restrict__ vpart,
                                              const float* __restrict__ b,
                                              const float* __restrict__ scal,
                                              _Float16* __restrict__ v_out) {
    const int t = threadIdx.x;
    const int col0 = blockIdx.x * 32;
    const int c = t & 31, seg = t >> 5;        // 8 segments
    const int pstep = BLK_A / 8;               // 64
    const _Float16* base = vpart + (size_t)(seg * pstep) * N_COLS + col0 + c;
    float s = 0.f;
    #pragma unroll 16
    for (int p = 0; p < pstep; ++p) s += (float)base[(size_t)p * N_COLS];
    __shared__ float lds[8][32];
    lds[seg][c] = s;
    __syncthreads();
    if (t < 32) {
        float tot = 0.f;
        #pragma unroll
        for (int g = 0; g < 8; ++g) tot += lds[g][t];
        const int j = col0 + t;
        v_out[j] = (_Float16)(b[j] * scal[1] * (VSCALE * KDEC) / tot);
    }
}

// ---------- loss = sum_ij u_i K_ij v_j M_ij, with M = -eps*ln(K) ----------
// Reads the 64 MB fp8 K (LLC-warm) instead of the cold 256 MB fp32 M:
// loss = -0.1 * sum u v K lnK, K = decoded/KDEC.
__global__ __launch_bounds__(256) void kern_loss(const unsigned char* __restrict__ K8,
                                                 const float* __restrict__ u_in,
                                                 const _Float16* __restrict__ v_in,
                                                 float* __restrict__ scal) {
    const int t = threadIdx.x;
    const int row0 = blockIdx.x * ROWS_L;
    const float invdec = 1.0f / KDEC;
    float vreg[32];
    #pragma unroll
    for (int k = 0; k < 2; ++k) {
        uint4 rv0 = *(const uint4*)(v_in + 16 * t + 4096 * k);
        uint4 rv1 = *(const uint4*)(v_in + 16 * t + 4096 * k + 8);
        half2_t h0 = u2h(rv0.x), h1 = u2h(rv0.y), h2 = u2h(rv0.z), h3 = u2h(rv0.w);
        half2_t h4 = u2h(rv1.x), h5 = u2h(rv1.y), h6 = u2h(rv1.z), h7 = u2h(rv1.w);
        float* vr = vreg + 16 * k;
        vr[0]  = (float)h0.x; vr[1]  = (float)h0.y; vr[2]  = (float)h1.x; vr[3]  = (float)h1.y;
        vr[4]  = (float)h2.x; vr[5]  = (float)h2.y; vr[6]  = (float)h3.x; vr[7]  = (float)h3.y;
        vr[8]  = (float)h4.x; vr[9]  = (float)h4.y; vr[10] = (float)h5.x; vr[11] = (float)h5.y;
        vr[12] = (float)h6.x; vr[13] = (float)h6.y; vr[14] = (float)h7.x; vr[15] = (float)h7.y;
    }
    float acc = 0.f;
    for (int r = 0; r < ROWS_L; ++r) {
        const int i = row0 + r;
        const float ui = u_in[i];
        const uint4* Kp = (const uint4*)(K8 + (size_t)i * N_COLS);
        #pragma unroll
        for (int k = 0; k < 2; ++k) {
            uint4 rk = Kp[t + 256 * k];
            half2_t kh[8];
            kh[0] = fp8pair_to_h2(rk.x); kh[1] = fp8pair_to_h2(rk.x >> 16);
            kh[2] = fp8pair_to_h2(rk.y); kh[3] = fp8pair_to_h2(rk.y >> 16);
            kh[4] = fp8pair_to_h2(rk.z); kh[5] = fp8pair_to_h2(rk.z >> 16);
            kh[6] = fp8pair_to_h2(rk.w); kh[7] = fp8pair_to_h2(rk.w >> 16);
            const float* vr = vreg + 16 * k;
            #pragma unroll
            for (int p = 0; p < 8; ++p) {
                float k0 = (float)kh[p].x * invdec;
                float k1 = (float)kh[p].y * invdec;
                acc += (ui * vr[2*p])   * k0 * __logf(k0);
                acc += (ui * vr[2*p+1]) * k1 * __logf(k1);
            }
        }
    }
    acc *= -0.1f;   // M = -eps * ln(K), eps = 0.1
    #pragma unroll
    for (int o = 32; o > 0; o >>= 1) acc += __shfl_down(acc, o);
    __shared__ float red[4];
    if ((t & 63) == 0) red[t >> 6] = acc;
    __syncthreads();
    if (t == 0) atomicAdd(&scal[2], red[0] + red[1] + red[2] + red[3]);
}

__global__ void kern_out(const float* __restrict__ scal, float* __restrict__ out) {
    if (threadIdx.x == 0 && blockIdx.x == 0) out[0] = scal[2];
}

// ---------- launch ----------
extern "C" void kernel_launch(void* const* d_in, const int* in_sizes, int n_in,
                              void* d_out, int out_size, void* d_ws, size_t ws_size,
                              hipStream_t stream) {
    const float* a = (const float*)d_in[0];
    const float* b = (const float*)d_in[1];
    const float* M = (const float*)d_in[2];

    char* ws = (char*)d_ws;
    float* scal        = (float*)ws;                                  // scalars
    float* u           = (float*)(ws + 1024);                         // 32 KB
    _Float16* v        = (_Float16*)(ws + 1024 + 32768);              // 16 KB
    _Float16* vpart    = (_Float16*)(ws + 1024 + 32768 + 16384);      // 512*8192*2 = 8 MB
    unsigned char* K8  = (unsigned char*)(ws + 1024 + 32768 + 16384 +
                                          (size_t)BLK_A * N_COLS * 2); // 64 MB fp8
    kern_setup<<<dim3(34), dim3(256), 0, stream>>>(a, b, scal, v);
    kern_kbuild<<<dim3(32768), dim3(256), 0, stream>>>(M, K8);
    for (int it = 0; it < NUM_ITER; ++it) {
        kern_A<<<dim3(BLK_A), dim3(THR_A), 0, stream>>>(K8, a, scal, v, u, vpart);
        kern_B<<<dim3(256), dim3(256), 0, stream>>>(vpart, b, scal, v);
    }
    kern_loss<<<dim3(BLK_L), dim3(256), 0, stream>>>(K8, u, v, scal);
    kern_out<<<dim3(1), dim3(64), 0, stream>>>(scal, (float*)d_out);
}